// Round 4
// baseline (1465.238 us; speedup 1.0000x reference)
//
#include <hip/hip_runtime.h>

#define E_EDGES 131072
#define FIN 16
#define FF 32

// ---- combo tables: 11 allowed (l1,l2,l3); blocks l=0:[0,1) l=1:[1,4) l=2:[4,9) ----
// order: (0,0,0)(0,1,1)(0,2,2)(1,0,1)(1,1,0)(1,1,2)(1,2,1)(2,0,2)(2,1,1)(2,2,0)(2,2,2)
constexpr int CIDX[11] = {0, 4, 8, 10, 12, 14, 16, 20, 22, 24, 26};  // (l1*3+l2)*3+l3
constexpr int CA0[11] = {0, 0, 0, 1, 1, 1, 1, 4, 4, 4, 4};
constexpr int CDA[11] = {1, 1, 1, 3, 3, 3, 3, 5, 5, 5, 5};
constexpr int CQ0[11] = {0, 1, 4, 0, 1, 1, 4, 0, 1, 4, 4};
constexpr int CDB[11] = {1, 3, 5, 1, 3, 3, 5, 1, 3, 5, 5};
constexpr int CC0[11] = {0, 1, 4, 1, 0, 4, 1, 4, 1, 0, 4};
constexpr int CDC[11] = {1, 3, 5, 3, 1, 5, 3, 5, 3, 1, 5};
constexpr int CZ0[11] = {0, 1, 4, 9, 18, 21, 36, 45, 70, 85, 90};  // cum(DA*DC), total 115

struct P8 { float* p[8]; };

// ---------------- Gaunt tensor via exact quadrature (matches reference) -------------
__global__ void gaunt_init(float* __restrict__ G) {
    __shared__ double Ys[128][9];
    __shared__ double wq[128];
    const double ct[8] = {
        -0.9602898564975363, -0.7966664774136267, -0.5255324099163290, -0.1834346424956498,
         0.1834346424956498,  0.5255324099163290,  0.7966664774136267,  0.9602898564975363};
    const double wgt[8] = {
        0.1012285362903763, 0.2223810344533745, 0.3137066458778873, 0.3626837833783620,
        0.3626837833783620, 0.3137066458778873, 0.2223810344533745, 0.1012285362903763};
    const double PI = 3.141592653589793238462643383279502884;
    int t = threadIdx.x;
    if (t < 128) {
        int iq = t >> 4, ip = t & 15;
        double c = ct[iq];
        double s = sqrt(1.0 - c * c);
        double phi = (double)ip * (2.0 * PI / 16.0);
        double x = s * cos(phi), y = s * sin(phi), z = c;
        double* Yp = Ys[t];
        Yp[0] = 0.28209479177387814;
        Yp[1] = 0.4886025119029199 * y;
        Yp[2] = 0.4886025119029199 * z;
        Yp[3] = 0.4886025119029199 * x;
        Yp[4] = 1.0925484305920792 * x * y;
        Yp[5] = 1.0925484305920792 * y * z;
        Yp[6] = 0.31539156525252005 * (3.0 * z * z - 1.0);
        Yp[7] = 1.0925484305920792 * x * z;
        Yp[8] = 0.5462742152960396 * (x * x - y * y);
        wq[t] = wgt[iq] * (2.0 * PI / 16.0);
    }
    __syncthreads();
    for (int idx = t; idx < 729; idx += blockDim.x) {
        int a = idx / 81, b = (idx / 9) % 9, cc = idx % 9;
        double sum = 0.0;
        for (int q = 0; q < 128; ++q) sum += wq[q] * Ys[q][a] * Ys[q][b] * Ys[q][cc];
        G[idx] = (float)sum;
    }
}

__global__ __launch_bounds__(256) void zero_kernel(float* __restrict__ p, size_t n) {
    size_t i = (size_t)blockIdx.x * 256 + threadIdx.x;
    if (i < n) p[i] = 0.f;
}

__global__ __launch_bounds__(256) void copy_kernel(const float4* __restrict__ src,
                                                   float4* __restrict__ dst, int n4) {
    int stride = gridDim.x * 256;
    for (int i = blockIdx.x * 256 + threadIdx.x; i < n4; i += stride) dst[i] = src[i];
}

// ---------------- embed: (E,9,16)@(16->32) into chunk-major regions ------------------
template <int CW>
__global__ __launch_bounds__(256) void embed2(
    const float* __restrict__ xin, const float* __restrict__ W0,
    const float* __restrict__ b0, P8 P) {
    constexpr int K = 32 / CW;
    int tid = threadIdx.x;
    int e = blockIdx.x * 8 + (tid >> 5);
    int f = tid & 31;
    int h = f / CW, fc = f % CW;
    float* Rh = P.p[0];
#pragma unroll
    for (int i = 1; i < K; ++i) Rh = (h == i) ? P.p[i] : Rh;
    const float* xr = xin + (size_t)e * 144;
#pragma unroll
    for (int c = 0; c < 9; ++c) {
        int l = (c == 0) ? 0 : ((c < 4) ? 1 : 2);
        const float* Wl = W0 + l * FIN * FF;
        float acc = (c == 0) ? b0[f] : 0.f;
#pragma unroll
        for (int q = 0; q < 4; ++q) {
            float4 xv = *(const float4*)&xr[c * 16 + q * 4];
            acc = fmaf(xv.x, Wl[(q * 4 + 0) * 32 + f], acc);
            acc = fmaf(xv.y, Wl[(q * 4 + 1) * 32 + f], acc);
            acc = fmaf(xv.z, Wl[(q * 4 + 2) * 32 + f], acc);
            acc = fmaf(xv.w, Wl[(q * 4 + 3) * 32 + f], acc);
        }
        Rh[((size_t)e * 9 + c) * CW + fc] = acc;
    }
}

// ---------------- phase-2 per-combo helper ------------------------------------------
template <int K, int CW>
__device__ __forceinline__ void combo2(const float* __restrict__ zs,
                                       const float* __restrict__ coefg, int fc,
                                       const float (&xa)[9], float (&out9)[9]) {
    constexpr int A0 = CA0[K], DA = CDA[K], C0 = CC0[K], DC = CDC[K], Z = CZ0[K];
    float m[DC] = {};
#pragma unroll
    for (int a = 0; a < DA; ++a)
#pragma unroll
        for (int c = 0; c < DC; ++c) m[c] = fmaf(xa[A0 + a], zs[Z + a * DC + c], m[c]);
    float cf = coefg[K * CW + fc];
#pragma unroll
    for (int c = 0; c < DC; ++c) out9[C0 + c] = fmaf(m[c], cf, out9[C0 + c]);
}

// ---------------- message pass, chunk h, chunk-major state ---------------------------
// Xh = region holding OLD slice h (gather reads); S = spare region pre-copied with Xh
// (atomic accumulate of messages -> S becomes the NEW slice h).
template <int CW>
__global__ __launch_bounds__(256) void mp2(
    const float* __restrict__ Xh, float* __restrict__ S,
    const float* __restrict__ coords,
    const int* __restrict__ dst, const int* __restrict__ src,
    const float* __restrict__ Wm,   // (27,32,32) this step
    const float* __restrict__ bm,   // (27,32)
    const float* __restrict__ Gglob, int h) {
    constexpr int EPB = 256 / CW;
    constexpr int BS = 256;
    __shared__ float gG[729];
    __shared__ float y_s[EPB][9];
    __shared__ float rad_s[EPB][33];
    __shared__ float W_s[11 * 32 * CW];
    __shared__ float coef_s[EPB][11 * CW];
    __shared__ float z_s[EPB][115];
    const int tid = threadIdx.x;
    for (int i = tid; i < 729; i += BS) gG[i] = Gglob[i];
    // stage W f-slice once per block: W_s[k][b][fc]
    for (int i = tid; i < 11 * 32 * CW; i += BS) {
        int k = i / (32 * CW);
        int r = i - k * (32 * CW);
        int b = r / CW, fc2 = r - b * CW;
        W_s[i] = Wm[CIDX[k] * 1024 + b * 32 + h * CW + fc2];
    }
    const int g = tid / CW, fc = tid % CW;
    const int f = h * CW + fc;
    const int e = blockIdx.x * EPB + g;
    const int d = dst[e], s0 = src[e];
    float rx = coords[3 * d + 0] - coords[3 * s0 + 0];
    float ry = coords[3 * d + 1] - coords[3 * s0 + 1];
    float rz = coords[3 * d + 2] - coords[3 * s0 + 2];
    float r = sqrtf(rx * rx + ry * ry + rz * rz + 1e-8f);
    float ux = rx / r, uy = ry / r, uz = rz / r;
    const float c0 = 0.28209479177387814f, c1 = 0.4886025119029199f;
    const float c2 = 1.0925484305920792f, c20 = 0.31539156525252005f, c22 = 0.5462742152960396f;
    float y9[9];
    y9[0] = c0;
    y9[1] = c1 * uy; y9[2] = c1 * uz; y9[3] = c1 * ux;
    y9[4] = c2 * ux * uy; y9[5] = c2 * uy * uz; y9[6] = c20 * (3.f * uz * uz - 1.f);
    y9[7] = c2 * ux * uz; y9[8] = c22 * (ux * ux - uy * uy);
#pragma unroll
    for (int b = fc; b < 9; b += CW) y_s[g][b] = y9[b];
    for (int b = fc; b < 32; b += CW) {
        float cb = (float)((double)b * (4.0 / 31.0));
        float dr = r - cb;
        rad_s[g][b] = expf(-dr * dr);
    }
    __syncthreads();
    // phase 1a: coef[g][k][fc] = bm + rad @ W  (block GEMM, W from LDS)
#pragma unroll
    for (int k = 0; k < 11; ++k) {
        float cacc = bm[CIDX[k] * 32 + f];
        const float* wk = &W_s[(k * 32) * CW + fc];
#pragma unroll
        for (int b = 0; b < 32; ++b) cacc = fmaf(rad_s[g][b], wk[b * CW], cacc);
        coef_s[g][k * CW + fc] = cacc;
    }
    // phase 1b: z[g][t] = sum_b Y[Q0+b] * G[(A0+a),(Q0+b),(C0+cc)]  (115 per edge)
    for (int idx = tid; idx < EPB * 115; idx += BS) {
        int gg = idx / 115;
        int t = idx - gg * 115;
        int A0 = 0, Q0 = 0, C0 = 0, DB = 1, DC = 1, Z = 0;
#pragma unroll
        for (int kk = 1; kk < 11; ++kk)
            if (t >= CZ0[kk]) { A0 = CA0[kk]; Q0 = CQ0[kk]; C0 = CC0[kk];
                                DB = CDB[kk]; DC = CDC[kk]; Z = CZ0[kk]; }
        int loc = t - Z;
        int a, cc;
        if (DC == 1) { a = loc; cc = 0; }
        else if (DC == 3) { a = loc / 3; cc = loc - a * 3; }
        else { a = loc / 5; cc = loc - a * 5; }
        float zv = 0.f;
        for (int b = 0; b < DB; ++b)
            zv = fmaf(y_s[gg][Q0 + b], gG[(A0 + a) * 81 + (Q0 + b) * 9 + (C0 + cc)], zv);
        z_s[gg][t] = zv;
    }
    __syncthreads();
    // phase 2: per (edge, f): m_c = sum_a x_a z[a][c]; out += coef * m; atomic scatter
    float xa[9];
#pragma unroll
    for (int a = 0; a < 9; ++a) xa[a] = Xh[((size_t)s0 * 9 + a) * CW + fc];
    float out9[9];
#pragma unroll
    for (int c = 0; c < 9; ++c) out9[c] = 0.f;
    const float* zs = z_s[g];
    const float* coefg = coef_s[g];
    combo2<0, CW>(zs, coefg, fc, xa, out9);
    combo2<1, CW>(zs, coefg, fc, xa, out9);
    combo2<2, CW>(zs, coefg, fc, xa, out9);
    combo2<3, CW>(zs, coefg, fc, xa, out9);
    combo2<4, CW>(zs, coefg, fc, xa, out9);
    combo2<5, CW>(zs, coefg, fc, xa, out9);
    combo2<6, CW>(zs, coefg, fc, xa, out9);
    combo2<7, CW>(zs, coefg, fc, xa, out9);
    combo2<8, CW>(zs, coefg, fc, xa, out9);
    combo2<9, CW>(zs, coefg, fc, xa, out9);
    combo2<10, CW>(zs, coefg, fc, xa, out9);
    float* yr = S + (size_t)d * 9 * CW;
#pragma unroll
    for (int c = 0; c < 9; ++c) atomicAdd(&yr[c * CW + fc], out9[c]);
}

// ---------------- final: dense(32->32) + gate + dense(32->1), persistent ------------
template <int CW>
__global__ __launch_bounds__(256) void final2(
    P8 P, const float* __restrict__ W1, const float* __restrict__ b1,
    const float* __restrict__ W2, const float* __restrict__ b2,
    float* __restrict__ out) {
    constexpr int K = 32 / CW;
    const float* R[K];
#pragma unroll
    for (int i = 0; i < K; ++i) R[i] = P.p[i];
    int lane = threadIdx.x & 63;
    int f = lane & 31;
    int wv = (blockIdx.x * 256 + threadIdx.x) >> 6;
    int nw = (gridDim.x * 256) >> 6;
    float w1r[3][32];
#pragma unroll
    for (int l = 0; l < 3; ++l)
#pragma unroll
        for (int gg = 0; gg < 32; ++gg) w1r[l][gg] = W1[(l * 32 + gg) * 32 + f];
    float w2r[3];
#pragma unroll
    for (int l = 0; l < 3; ++l) w2r[l] = W2[l * 32 + f];
    float b1f = b1[f], b20 = b2[0];
    for (int ep = wv; ep < E_EDGES / 2; ep += nw) {
        int e = ep * 2 + (lane >> 5);
        float t[9];
#pragma unroll
        for (int c = 0; c < 9; ++c) {
            int l = (c == 0) ? 0 : ((c < 4) ? 1 : 2);
            float acc = (c == 0) ? b1f : 0.f;
#pragma unroll
            for (int q = 0; q < 8; ++q) {
                const float* Rq = R[(q * 4) / CW];
                float4 xv = *(const float4*)&Rq[((size_t)e * 9 + c) * CW + ((q * 4) % CW)];
                acc = fmaf(xv.x, w1r[l][q * 4 + 0], acc);
                acc = fmaf(xv.y, w1r[l][q * 4 + 1], acc);
                acc = fmaf(xv.z, w1r[l][q * 4 + 2], acc);
                acc = fmaf(xv.w, w1r[l][q * 4 + 3], acc);
            }
            t[c] = acc;
        }
        float gate = (t[0] > 0.f) ? 1.f : 0.f;
#pragma unroll
        for (int c = 0; c < 9; ++c) {
            int l = (c == 0) ? 0 : ((c < 4) ? 1 : 2);
            float v = t[c] * gate * w2r[l];
#pragma unroll
            for (int off = 16; off; off >>= 1) v += __shfl_xor(v, off, 32);
            if (f == 0) out[(size_t)e * 9 + c] = v + ((c == 0) ? b20 : 0.f);
        }
    }
}

// ---------------- driver -------------------------------------------------------------
template <int CW>
static void run_all(const float* x_dftb, const float* coords, const int* dst,
                    const int* src, const float* W0, const float* b0,
                    const float* Wmp, const float* bmp, const float* W1,
                    const float* b1, const float* W2, const float* b2,
                    float* out, char* ws, hipStream_t stream) {
    constexpr int K = 32 / CW;
    constexpr int EPB = 256 / CW;
    size_t sliceB = (size_t)E_EDGES * 9 * CW * sizeof(float);
    float* G = (float*)ws;
    float* reg[K + 1];
    for (int i = 0; i <= K; ++i) reg[i] = (float*)(ws + 4096 + (size_t)i * sliceB);
    int cur[K];
    for (int i = 0; i < K; ++i) cur[i] = i;
    int spare = K;

    gaunt_init<<<1, 256, 0, stream>>>(G);
    P8 Pe;
    for (int i = 0; i < 8; ++i) Pe.p[i] = reg[(i < K) ? cur[i] : 0];
    embed2<CW><<<E_EDGES / 8, 256, 0, stream>>>(x_dftb, W0, b0, Pe);

    int n4 = (int)(sliceB / 16);
    for (int step = 0; step < 2; ++step) {
        const float* Ws = Wmp + step * 27648;
        const float* bs = bmp + step * 864;
        for (int h = 0; h < K; ++h) {
            copy_kernel<<<2048, 256, 0, stream>>>((const float4*)reg[cur[h]],
                                                  (float4*)reg[spare], n4);
            mp2<CW><<<E_EDGES / EPB, 256, 0, stream>>>(
                reg[cur[h]], reg[spare], coords, dst, src, Ws, bs, G, h);
            int tmp = cur[h]; cur[h] = spare; spare = tmp;
        }
    }
    P8 Pf;
    for (int i = 0; i < 8; ++i) Pf.p[i] = reg[(i < K) ? cur[i] : 0];
    final2<CW><<<2048, 256, 0, stream>>>(Pf, W1, b1, W2, b2, out);
}

extern "C" void kernel_launch(void* const* d_in, const int* in_sizes, int n_in,
                              void* d_out, int out_size, void* d_ws, size_t ws_size,
                              hipStream_t stream) {
    const float* x_dftb = (const float*)d_in[0];
    const float* coords = (const float*)d_in[1];
    const int* dst = (const int*)d_in[2];
    const int* src = (const int*)d_in[3];
    const float* W0 = (const float*)d_in[4];
    const float* b0 = (const float*)d_in[5];
    const float* Wmp = (const float*)d_in[6];
    const float* bmp = (const float*)d_in[7];
    const float* W1 = (const float*)d_in[8];
    const float* b1 = (const float*)d_in[9];
    const float* W2 = (const float*)d_in[10];
    const float* b2 = (const float*)d_in[11];
    float* out = (float*)d_out;
    char* ws = (char*)d_ws;

    // choose widest chunk whose (K+1) equal regions fit:
    // CW=32: 2x151MB=302; CW=16: 3x75.5=227; CW=8: 5x37.8=189; CW=4: 9x18.9=170 (+4KB)
    int CW = 0;
    for (int w = 32; w >= 4; w >>= 1) {
        size_t sliceB = (size_t)E_EDGES * 9 * w * sizeof(float);
        if (4096 + (size_t)(32 / w + 1) * sliceB <= ws_size) { CW = w; break; }
    }
    if (CW == 0) {
        zero_kernel<<<(out_size + 255) / 256, 256, 0, stream>>>(out, (size_t)out_size);
        return;
    }
    switch (CW) {
        case 32: run_all<32>(x_dftb, coords, dst, src, W0, b0, Wmp, bmp, W1, b1, W2, b2, out, ws, stream); break;
        case 16: run_all<16>(x_dftb, coords, dst, src, W0, b0, Wmp, bmp, W1, b1, W2, b2, out, ws, stream); break;
        case 8:  run_all<8 >(x_dftb, coords, dst, src, W0, b0, Wmp, bmp, W1, b1, W2, b2, out, ws, stream); break;
        default: run_all<4 >(x_dftb, coords, dst, src, W0, b0, Wmp, bmp, W1, b1, W2, b2, out, ws, stream); break;
    }
}